// Round 7
// baseline (147.074 us; speedup 1.0000x reference)
//
#include <hip/hip_runtime.h>
#include <hip/hip_bf16.h>

#define BSZ 8192
#define BTZ 8192
#define DD 64
#define NC 10
#define SHIFT2 20.0f   // log2-domain shift
#define LN2 0.69314718055994531f
#define LOG2E 1.44269504088896341f

typedef __attribute__((ext_vector_type(8))) short bf16x8;
typedef __attribute__((ext_vector_type(4))) float f32x4;

#if defined(__has_builtin)
#if __has_builtin(__builtin_amdgcn_exp2f)
#define EXP2(x) __builtin_amdgcn_exp2f(x)
#else
#define EXP2(x) exp2f(x)
#endif
#else
#define EXP2(x) exp2f(x)
#endif

__device__ __forceinline__ unsigned short f2bf_rne(float f) {
    unsigned int u = __float_as_uint(f);
    u += 0x7FFFu + ((u >> 16) & 1u);
    return (unsigned short)(u >> 16);
}

// Kernel AB: blocks 0..511 convert f32->bf16 (src pre-scaled by log2e).
// Blocks 512..543: per-tgt top2/conf/cls -> colmeta {cb2, cls}, per-block
// confcount partials, S zero, gcnt/gACC zero. Label histogram self-computed
// per block via register compare-accumulate (no global atomics).
__global__ __launch_bounds__(256) void kAB(
    const float4* __restrict__ src4, const float4* __restrict__ tgt4,
    const int* __restrict__ labels, const float* __restrict__ logits,
    ushort4* __restrict__ srcb, ushort4* __restrict__ tgtb,
    float* __restrict__ S, float* __restrict__ counts,
    float* __restrict__ cc_part, int2* __restrict__ colmeta,
    int* __restrict__ gcnt, float* __restrict__ gACC)
{
    int t = threadIdx.x;
    if (blockIdx.x < 512) {
        int tid = blockIdx.x * 256 + t;   // 131072 threads = 8192*64/4
        float4 s = src4[tid];
        ushort4 os;
        os.x = f2bf_rne(s.x * LOG2E); os.y = f2bf_rne(s.y * LOG2E);
        os.z = f2bf_rne(s.z * LOG2E); os.w = f2bf_rne(s.w * LOG2E);
        srcb[tid] = os;
        float4 v = tgt4[tid];
        ushort4 ot; ot.x = f2bf_rne(v.x); ot.y = f2bf_rne(v.y);
        ot.z = f2bf_rne(v.z); ot.w = f2bf_rne(v.w);
        tgtb[tid] = ot;
        return;
    }
    __shared__ float lcnt[NC];
    __shared__ float hist[NC];
    __shared__ float hred[4][NC];
    int b = blockIdx.x - 512;
    int i = b * 256 + t;
    int w = t >> 6, lane = t & 63;

    // self-histogram of all src labels (each block redundantly; cheap)
    float c10[NC];
    #pragma unroll
    for (int c = 0; c < NC; ++c) c10[c] = 0.0f;
    for (int k = 0; k < 32; ++k) {
        int lab = labels[t + 256 * k];
        #pragma unroll
        for (int c = 0; c < NC; ++c) c10[c] += (lab == c) ? 1.0f : 0.0f;
    }
    #pragma unroll
    for (int c = 0; c < NC; ++c) {
        float v = c10[c];
        #pragma unroll
        for (int m = 1; m < 64; m <<= 1) v += __shfl_xor(v, m);
        if (lane == 0) hred[w][c] = v;
    }
    if (t < NC) hist[t] = 0.0f;
    __syncthreads();
    if (t < NC) lcnt[t] = hred[0][t] + hred[1][t] + hred[2][t] + hred[3][t];
    __syncthreads();
    if (b == 0) {
        if (t < NC) counts[t] = lcnt[t];
        if (t == 64) *gcnt = 0;
        if (t == 65) gACC[0] = 0.0f;
    }

    float m1 = -3.0e38f, m2 = -3.0e38f; int cls = 0;
    #pragma unroll
    for (int c = 0; c < NC; ++c) {
        float v = logits[i * NC + c];
        if (v > m1) { m2 = m1; m1 = v; cls = c; }
        else if (v > m2) { m2 = v; }
    }
    bool conf = (m1 - m2) >= 0.1f;
    float cnt = lcnt[cls];
    bool live = conf && (cnt > 0.0f);
    float cb2 = live ? (log2f(cnt) - SHIFT2) : -1.0e30f;
    colmeta[i] = make_int2(__float_as_int(cb2), live ? cls : 255);
    S[i] = 0.0f;
    if (conf) atomicAdd(&hist[cls], 1.0f);
    __syncthreads();
    if (t < NC) cc_part[b * NC + t] = hist[t];
}

// Kernel C: 2048 blocks (R3 structure: full occupancy, no launch-bounds cap).
// Block = 64 rows x 512 cols (colchunk = bid&15, rowg = bid>>4); 4 waves split
// columns (128 each), B loaded inside the 8-iteration column loop (unroll 2).
// Inline t1p = sum of masked acc (log2 domain, bias included — corrected
// analytically in the finale). Last block (atomic counter) runs the finale.
__global__ __launch_bounds__(256) void kC(
    const unsigned short* __restrict__ srcb, const unsigned short* __restrict__ tgtb,
    const int2* __restrict__ colmeta, const int* __restrict__ labels,
    float* __restrict__ S, const float* __restrict__ counts,
    const float* __restrict__ cc_part,
    float* __restrict__ gACC, int* __restrict__ gcnt,
    float* __restrict__ out)
{
    __shared__ float lds[4][64];
    __shared__ float t1red[4];
    __shared__ int isLast;
    __shared__ float ccs[NC];
    __shared__ float redv[4];
    int t = threadIdx.x;
    int w = t >> 6;
    int lane = t & 63;
    int l15 = lane & 15;
    int quad = lane >> 4;
    int colchunk = blockIdx.x & 15;
    int rowg = blockIdx.x >> 4;
    int row_base = rowg * 64;

    bf16x8 a[4][2];
    int rlp[4];
    #pragma unroll
    for (int mb = 0; mb < 4; ++mb) {
        const bf16x8* p = (const bf16x8*)(srcb + (size_t)(row_base + mb * 16 + l15) * DD + quad * 8);
        a[mb][0] = p[0];   // k = quad*8 + j
        a[mb][1] = p[4];   // k = 32 + quad*8 + j
        int4 rl = ((const int4*)labels)[(row_base + mb * 16 + quad * 4) >> 2];
        rlp[mb] = (rl.x & 255) | ((rl.y & 255) << 8) | ((rl.z & 255) << 16) | ((rl.w & 255) << 24);
    }

    float rs[4][4];
    #pragma unroll
    for (int mb = 0; mb < 4; ++mb)
        #pragma unroll
        for (int r = 0; r < 4; ++r) rs[mb][r] = 0.0f;
    float t1p = 0.0f;

    int col0 = colchunk * 512 + w * 128;
    #pragma unroll 2
    for (int ct = 0; ct < 8; ++ct) {
        int ci = col0 + ct * 16 + l15;
        const bf16x8* q = (const bf16x8*)(tgtb + (size_t)ci * DD + quad * 8);
        bf16x8 b0 = q[0];
        bf16x8 b1 = q[4];
        int2 meta = colmeta[ci];
        float cb2 = __int_as_float(meta.x);
        int ccls = meta.y;
        #pragma unroll
        for (int mb = 0; mb < 4; ++mb) {
            f32x4 acc = {cb2, cb2, cb2, cb2};
            acc = __builtin_amdgcn_mfma_f32_16x16x32_bf16(a[mb][0], b0, acc, 0, 0, 0);
            acc = __builtin_amdgcn_mfma_f32_16x16x32_bf16(a[mb][1], b1, acc, 0, 0, 0);
            #pragma unroll
            for (int r = 0; r < 4; ++r) {
                float e = acc[r];
                rs[mb][r] += EXP2(e);
                t1p += (((rlp[mb] >> (8 * r)) & 255) == ccls) ? e : 0.0f;
            }
        }
    }

    // row sums: reduce over 16 column-lanes per quad, cross-wave via LDS
    #pragma unroll
    for (int mb = 0; mb < 4; ++mb) {
        #pragma unroll
        for (int r = 0; r < 4; ++r) {
            float v = rs[mb][r];
            v += __shfl_xor(v, 1);
            v += __shfl_xor(v, 2);
            v += __shfl_xor(v, 4);
            v += __shfl_xor(v, 8);
            if (l15 == 0) lds[w][mb * 16 + quad * 4 + r] = v;
        }
    }
    #pragma unroll
    for (int m = 1; m < 64; m <<= 1) t1p += __shfl_xor(t1p, m);
    if (lane == 0) t1red[w] = t1p;
    __syncthreads();
    if (t < 64)
        atomicAdd(&S[row_base + t], lds[0][t] + lds[1][t] + lds[2][t] + lds[3][t]);
    if (t == 0) {
        atomicAdd(&gACC[0], t1red[0] + t1red[1] + t1red[2] + t1red[3]);
        __threadfence();
        int old = atomicAdd(gcnt, 1);
        isLast = (old == 2047) ? 1 : 0;
    }
    __syncthreads();
    if (!isLast) return;

    // ---- finale (last block only) ----
    __threadfence();
    if (t < NC) {
        float s = 0.0f;
        #pragma unroll
        for (int k = 0; k < 32; ++k) s += cc_part[k * NC + t];
        ccs[t] = s;
    }
    __syncthreads();
    float acc2 = 0.0f;   // -termL
    for (int j = t; j < BSZ; j += 256) {
        float Sj = __hip_atomic_load(&S[j], __ATOMIC_RELAXED, __HIP_MEMORY_SCOPE_AGENT);
        float L = (log2f(Sj) + SHIFT2) * LN2;
        acc2 -= ccs[labels[j]] * L;
    }
    #pragma unroll
    for (int m = 1; m < 64; m <<= 1) acc2 += __shfl_xor(acc2, m);
    if (lane == 0) redv[w] = acc2;
    __syncthreads();
    if (t == 0) {
        float negL = redv[0] + redv[1] + redv[2] + redv[3];
        float t1sum = __hip_atomic_load(&gACC[0], __ATOMIC_RELAXED, __HIP_MEMORY_SCOPE_AGENT);
        float corr = 0.0f, P = 0.0f;
        #pragma unroll
        for (int c = 0; c < NC; ++c) {
            float n = counts[c];
            if (n > 0.0f) {
                corr += ccs[c] * n * (log2f(n) - SHIFT2);
                P += n * ccs[c];
            }
        }
        float term1 = (t1sum - corr) * LN2;
        out[0] = (term1 + negL) / (-(float)BSZ * P);
    }
}

extern "C" void kernel_launch(void* const* d_in, const int* in_sizes, int n_in,
                              void* d_out, int out_size, void* d_ws, size_t ws_size,
                              hipStream_t stream) {
    const float* src    = (const float*)d_in[0];
    const int*   labels = (const int*)d_in[1];
    const float* tgt    = (const float*)d_in[2];
    const float* logits = (const float*)d_in[3];

    char* ws = (char*)d_ws;
    float* S        = (float*)(ws + 0);          // 32768 B (zeroed by kAB)
    float* counts   = (float*)(ws + 32768);      // 40 B  (kAB b==0)
    int*   gcnt     = (int*)(ws + 32832);        // 4 B   (zeroed by kAB)
    float* gACC     = (float*)(ws + 32896);      // 4 B   (zeroed by kAB)
    float* cc_part  = (float*)(ws + 32960);      // 1280 B (kAB)
    int2*  colmeta  = (int2*)(ws + 40960);       // 65536 B (kAB)
    unsigned short* srcb = (unsigned short*)(ws + 114688);            // 1 MiB
    unsigned short* tgtb = (unsigned short*)(ws + 114688 + 1048576);  // 1 MiB

    kAB<<<544, 256, 0, stream>>>((const float4*)src, (const float4*)tgt, labels,
                                 logits, (ushort4*)srcb, (ushort4*)tgtb,
                                 S, counts, cc_part, colmeta, gcnt, gACC);
    kC<<<2048, 256, 0, stream>>>(srcb, tgtb, colmeta, labels,
                                 S, counts, cc_part, gACC, gcnt, (float*)d_out);
}

// Round 8
// 111.382 us; speedup vs baseline: 1.3204x; 1.3204x over previous
//
#include <hip/hip_runtime.h>
#include <hip/hip_bf16.h>

#define BSZ 8192
#define BTZ 8192
#define DD 64
#define NC 10
#define SHIFT2 20.0f   // log2-domain shift
#define LN2 0.69314718055994531f
#define LOG2E 1.44269504088896341f

typedef __attribute__((ext_vector_type(8))) short bf16x8;
typedef __attribute__((ext_vector_type(4))) float f32x4;

#if defined(__has_builtin)
#if __has_builtin(__builtin_amdgcn_exp2f)
#define EXP2(x) __builtin_amdgcn_exp2f(x)
#else
#define EXP2(x) exp2f(x)
#endif
#else
#define EXP2(x) exp2f(x)
#endif

__device__ __forceinline__ unsigned short f2bf_rne(float f) {
    unsigned int u = __float_as_uint(f);
    u += 0x7FFFu + ((u >> 16) & 1u);
    return (unsigned short)(u >> 16);
}

// Kernel A: f32 -> bf16 (RNE); src pre-scaled by log2(e). Blocks 0..31 also
// build per-block label-histogram partials (LDS only -> slot; NO global atomics).
__global__ void kA(const float4* __restrict__ src4, const float4* __restrict__ tgt4,
                   const int* __restrict__ labels,
                   ushort4* __restrict__ srcb, ushort4* __restrict__ tgtb,
                   float* __restrict__ cnt_part) {
    __shared__ float hist[NC];
    int t = threadIdx.x;
    int tid = blockIdx.x * 256 + t;   // 131072 threads = 8192*64/4
    float4 s = src4[tid];
    ushort4 os;
    os.x = f2bf_rne(s.x * LOG2E); os.y = f2bf_rne(s.y * LOG2E);
    os.z = f2bf_rne(s.z * LOG2E); os.w = f2bf_rne(s.w * LOG2E);
    srcb[tid] = os;
    float4 v = tgt4[tid];
    ushort4 ot; ot.x = f2bf_rne(v.x); ot.y = f2bf_rne(v.y);
    ot.z = f2bf_rne(v.z); ot.w = f2bf_rne(v.w);
    tgtb[tid] = ot;

    if (blockIdx.x < 32) {
        if (t < NC) hist[t] = 0.0f;
        __syncthreads();
        atomicAdd(&hist[labels[tid]], 1.0f);
        __syncthreads();
        if (t < NC) cnt_part[blockIdx.x * NC + t] = hist[t];
    }
}

// Kernel B: per-tgt top2/cls/conf -> colbias (log2 domain) + cls byte;
// per-block confcount partials; zeroes S. counts reduced from partials in LDS.
__global__ void kB(const float* __restrict__ logits,
                   const float* __restrict__ cnt_part,
                   float* __restrict__ colbias, unsigned char* __restrict__ cls8,
                   float* __restrict__ cc_part, float* __restrict__ S) {
    __shared__ float lcnt[NC];
    __shared__ float hist[NC];
    int t = threadIdx.x;
    int i = blockIdx.x * 256 + t;

    if (t < NC) {
        float c = 0.0f;
        #pragma unroll
        for (int b = 0; b < 32; ++b) c += cnt_part[b * NC + t];
        lcnt[t] = c;
        hist[t] = 0.0f;
    }

    float m1 = -3.0e38f, m2 = -3.0e38f; int cls = 0;
    #pragma unroll
    for (int c = 0; c < NC; ++c) {
        float v = logits[i * NC + c];
        if (v > m1) { m2 = m1; m1 = v; cls = c; }
        else if (v > m2) { m2 = v; }
    }
    bool conf = (m1 - m2) >= 0.1f;
    __syncthreads();
    float cnt = lcnt[cls];
    bool live = conf && (cnt > 0.0f);
    colbias[i] = live ? (log2f(cnt) - SHIFT2) : -1.0e30f;
    cls8[i] = live ? (unsigned char)cls : (unsigned char)255;
    S[i] = 0.0f;
    if (conf) atomicAdd(&hist[cls], 1.0f);
    __syncthreads();
    if (t < NC) cc_part[blockIdx.x * NC + t] = hist[t];
}

// Kernel C: fused bf16 MFMA GEMM + exp2 row-sum + inline term1 (pair-sum of M).
// Grid: 2048 blocks = 128 rowgroups x 16 colchunks. Block = 64 rows x 512 cols;
// 4 waves split columns. Column bias folded into MFMA accumulator init.
// R8 change (the ONLY delta vs the 109.9 µs champion): explicit 1-iteration
// software pipeline — next tile's b0/b1/colbias/cls8 loads issue before the
// current tile's MFMA+exp2 compute, so load->use spans a full iteration.
__global__ __launch_bounds__(256) void kC(const unsigned short* __restrict__ srcb,
                                          const unsigned short* __restrict__ tgtb,
                                          const float* __restrict__ colbias,
                                          const unsigned char* __restrict__ cls8,
                                          const int* __restrict__ labels,
                                          float* __restrict__ S,
                                          float* __restrict__ term1_part) {
    __shared__ float lds[4][64];
    __shared__ float t1red[4];
    int t = threadIdx.x;
    int w = t >> 6;
    int lane = t & 63;
    int l15 = lane & 15;
    int quad = lane >> 4;
    int colchunk = blockIdx.x & 15;
    int rowg = blockIdx.x >> 4;
    int row_base = rowg * 64;

    bf16x8 a[4][2];
    int rl[4][4];
    #pragma unroll
    for (int mb = 0; mb < 4; ++mb) {
        const bf16x8* p = (const bf16x8*)(srcb + (size_t)(row_base + mb * 16 + l15) * DD + quad * 8);
        a[mb][0] = p[0];   // k = quad*8 + j
        a[mb][1] = p[4];   // k = 32 + quad*8 + j
        #pragma unroll
        for (int r = 0; r < 4; ++r)
            rl[mb][r] = labels[row_base + mb * 16 + quad * 4 + r];
    }

    float rs[4][4];
    #pragma unroll
    for (int mb = 0; mb < 4; ++mb)
        #pragma unroll
        for (int r = 0; r < 4; ++r) rs[mb][r] = 0.0f;
    float t1p = 0.0f;

    int col0 = colchunk * 512 + w * 128;
    // prologue: load tile 0
    const bf16x8* q0 = (const bf16x8*)(tgtb + (size_t)(col0 + l15) * DD + quad * 8);
    bf16x8 b0 = q0[0];
    bf16x8 b1 = q0[4];
    float cb2 = colbias[col0 + l15];
    int ccls = (int)cls8[col0 + l15];

    #pragma unroll 2
    for (int ct = 0; ct < 8; ++ct) {
        // prefetch tile ct+1 before computing tile ct
        bf16x8 nb0, nb1;
        float ncb2 = -1.0e30f;
        int nccls = 255;
        if (ct < 7) {
            int cc = col0 + (ct + 1) * 16 + l15;
            const bf16x8* nq = (const bf16x8*)(tgtb + (size_t)cc * DD + quad * 8);
            nb0 = nq[0];
            nb1 = nq[4];
            ncb2 = colbias[cc];
            nccls = (int)cls8[cc];
        }
        #pragma unroll
        for (int mb = 0; mb < 4; ++mb) {
            f32x4 acc = {cb2, cb2, cb2, cb2};
            acc = __builtin_amdgcn_mfma_f32_16x16x32_bf16(a[mb][0], b0, acc, 0, 0, 0);
            acc = __builtin_amdgcn_mfma_f32_16x16x32_bf16(a[mb][1], b1, acc, 0, 0, 0);
            #pragma unroll
            for (int r = 0; r < 4; ++r) {
                float e = acc[r];
                rs[mb][r] += EXP2(e);
                t1p += (ccls == rl[mb][r]) ? (e - cb2) : 0.0f;
            }
        }
        b0 = nb0; b1 = nb1; cb2 = ncb2; ccls = nccls;
    }

    // row sums: reduce over 16 column-lanes per quad, cross-wave via LDS
    #pragma unroll
    for (int mb = 0; mb < 4; ++mb) {
        #pragma unroll
        for (int r = 0; r < 4; ++r) {
            float v = rs[mb][r];
            v += __shfl_xor(v, 1);
            v += __shfl_xor(v, 2);
            v += __shfl_xor(v, 4);
            v += __shfl_xor(v, 8);
            if (l15 == 0) lds[w][mb * 16 + quad * 4 + r] = v;
        }
    }
    // term1: full-wave reduce then LDS
    float tv = t1p;
    #pragma unroll
    for (int m = 1; m < 64; m <<= 1) tv += __shfl_xor(tv, m);
    if (lane == 0) t1red[w] = tv;
    __syncthreads();
    if (t < 64)
        atomicAdd(&S[row_base + t], lds[0][t] + lds[1][t] + lds[2][t] + lds[3][t]);
    if (t == 128)
        term1_part[blockIdx.x] = t1red[0] + t1red[1] + t1red[2] + t1red[3];
}

// Kernel D: single-block finale.
__global__ void kD(const float* __restrict__ S, const int* __restrict__ labels,
                   const float* __restrict__ cnt_part, const float* __restrict__ cc_part,
                   const float* __restrict__ term1_part,
                   float* __restrict__ out) {
    __shared__ float counts[NC], cc[NC];
    int t = threadIdx.x;
    if (t < NC) {
        float c0 = 0.0f, c1 = 0.0f;
        #pragma unroll
        for (int b = 0; b < 32; ++b) { c0 += cnt_part[b * NC + t]; c1 += cc_part[b * NC + t]; }
        counts[t] = c0; cc[t] = c1;
    }
    __syncthreads();

    float termL = 0.0f, term1 = 0.0f, P = 0.0f;
    for (int j = t; j < BSZ; j += 256) {
        float L = (log2f(S[j]) + SHIFT2) * LN2;
        termL += cc[labels[j]] * L;
    }
    for (int o = t; o < 2048; o += 256) term1 += term1_part[o];
    if (t < NC) P = counts[t] * cc[t];

    __shared__ float redL[4], red1[4], redP[4];
    int w = t >> 6, lane = t & 63;
    float v1 = termL, v2 = term1, v3 = P;
    #pragma unroll
    for (int m = 1; m < 64; m <<= 1) {
        v1 += __shfl_xor(v1, m);
        v2 += __shfl_xor(v2, m);
        v3 += __shfl_xor(v3, m);
    }
    if (lane == 0) { redL[w] = v1; red1[w] = v2; redP[w] = v3; }
    __syncthreads();
    if (t == 0) {
        float tl = redL[0] + redL[1] + redL[2] + redL[3];
        float t1 = (red1[0] + red1[1] + red1[2] + red1[3]) * LN2;
        float p  = redP[0] + redP[1] + redP[2] + redP[3];
        out[0] = (t1 - tl) / (-1.0f * (float)BSZ * p);
    }
}

extern "C" void kernel_launch(void* const* d_in, const int* in_sizes, int n_in,
                              void* d_out, int out_size, void* d_ws, size_t ws_size,
                              hipStream_t stream) {
    const float* src    = (const float*)d_in[0];
    const int*   labels = (const int*)d_in[1];
    const float* tgt    = (const float*)d_in[2];
    const float* logits = (const float*)d_in[3];

    char* ws = (char*)d_ws;
    float* S          = (float*)(ws + 0);        // 32768 B, zeroed by kB
    float* cnt_part   = (float*)(ws + 32768);    // 1280 B, written by kA
    float* cc_part    = (float*)(ws + 34048);    // 1280 B, written by kB
    float* term1_part = (float*)(ws + 35328);    // 8192 B, written by kC
    float* colbias    = (float*)(ws + 65536);    // 32768 B, written by kB
    unsigned char* cls8 = (unsigned char*)(ws + 98304);   // 8192 B, written by kB
    unsigned short* srcb = (unsigned short*)(ws + 131072);            // 1 MiB
    unsigned short* tgtb = (unsigned short*)(ws + 131072 + 1048576);  // 1 MiB

    kA<<<512, 256, 0, stream>>>((const float4*)src, (const float4*)tgt, labels,
                                (ushort4*)srcb, (ushort4*)tgtb, cnt_part);
    kB<<<32, 256, 0, stream>>>(logits, cnt_part, colbias, cls8, cc_part, S);
    kC<<<2048, 256, 0, stream>>>(srcb, tgtb, colbias, cls8, labels, S, term1_part);
    kD<<<1, 256, 0, stream>>>(S, labels, cnt_part, cc_part, term1_part, (float*)d_out);
}